// Round 5
// baseline (124.455 us; speedup 1.0000x reference)
//
#include <hip/hip_runtime.h>
#include <math.h>

#define H      128
#define FCN    400
#define L1N    500
#define L2N    63
#define STEPS  65536
#define NBLK   100
#define NWAVE  (NBLK * 4)   // 400 waves
#define TAG    0x13572468u

// slot indices into the u64 slot array in d_ws
#define HB0 0
#define HB1 128
#define HB2 256
#define FCO 384
#define L1O 784

typedef unsigned long long u64;

__device__ __forceinline__ float sigmoidf_(float v) {
    return 1.0f / (1.0f + expf(-v));
}

__device__ __forceinline__ float wave_reduce(float v) {
#pragma unroll
    for (int off = 32; off > 0; off >>= 1)
        v += __shfl_down(v, off, 64);
    return v;
}

// Tagged-slot dataflow: value and tag share one 64-bit word, so a relaxed
// atomic load that sees the tag also sees the value (agent scope -> LLC,
// coherent across the non-coherent per-XCD L2s). Harness re-poisons d_ws
// with 0xAA before every launch, which clears all tags.
__device__ __forceinline__ void slot_store(u64* s, float v) {
    union { float f; unsigned u; } c; c.f = v;
    u64 p = ((u64)TAG << 32) | (u64)c.u;
    __hip_atomic_store(s, p, __ATOMIC_RELEASE, __HIP_MEMORY_SCOPE_AGENT);
}
__device__ __forceinline__ float slot_wait(const u64* s) {
    u64 v = __hip_atomic_load(s, __ATOMIC_RELAXED, __HIP_MEMORY_SCOPE_AGENT);
    while ((unsigned)(v >> 32) != TAG) {
        __builtin_amdgcn_s_sleep(1);
        v = __hip_atomic_load(s, __ATOMIC_RELAXED, __HIP_MEMORY_SCOPE_AGENT);
    }
    union { unsigned u; float f; } c; c.u = (unsigned)v;
    return c.f;
}

__device__ __forceinline__ float dot2(float2 w, float2 x) {
    return fmaf(w.x, x.x, w.y * x.y);
}
__device__ __forceinline__ float dot4(float4 w, float4 x) {
    return fmaf(w.x, x.x, fmaf(w.y, x.y, fmaf(w.z, x.z, w.w * x.w)));
}

__global__ __launch_bounds__(256) void fused_kernel(
    const float* __restrict__ x_last,  // [H]
    const float* __restrict__ W_ih,    // [3, 4H, H]
    const float* __restrict__ b_ih,    // [3, 4H]
    const float* __restrict__ b_hh,    // [3, 4H]
    const float* __restrict__ W_fc,    // [FCN, H]
    const float* __restrict__ b_fc,
    const float* __restrict__ W_l1,    // [L1N, FCN]
    const float* __restrict__ b_l1,
    const float* __restrict__ W_l2,    // [L2N, L1N]
    const float* __restrict__ b_l2,
    u64* __restrict__ slots,           // ws: tagged dataflow slots
    float* __restrict__ out)           // [L2N]
{
    const int tid  = threadIdx.x;
    const int lane = tid & 63;
    const int gw   = (blockIdx.x << 2) | (tid >> 6);  // 0..399

    const float4 z4 = make_float4(0.f, 0.f, 0.f, 0.f);
    const bool lstm_role = (gw < H);

    // ============ PREFETCH ALL WEIGHTS (no activation dependence) =========
    // x_last first: needed soonest
    float2 xv0 = make_float2(0.f, 0.f);
    if (lstm_role) xv0 = ((const float2*)x_last)[lane];

    float2 wA[3][3];
    float  bA[3][3];
    if (lstm_role) {
#pragma unroll
        for (int l = 0; l < 3; ++l) {
            const float* Wl = W_ih + (size_t)l * 4 * H * H;
            wA[l][0] = ((const float2*)(Wl + (size_t)(0 * H + gw) * H))[lane];
            wA[l][1] = ((const float2*)(Wl + (size_t)(2 * H + gw) * H))[lane];
            wA[l][2] = ((const float2*)(Wl + (size_t)(3 * H + gw) * H))[lane];
            bA[l][0] = b_ih[l * 4 * H + 0 * H + gw] + b_hh[l * 4 * H + 0 * H + gw];
            bA[l][1] = b_ih[l * 4 * H + 2 * H + gw] + b_hh[l * 4 * H + 2 * H + gw];
            bA[l][2] = b_ih[l * 4 * H + 3 * H + gw] + b_hh[l * 4 * H + 3 * H + gw];
        }
    }

    // FC row gw (gw always < 400)
    const float2 wfc = ((const float2*)(W_fc + (size_t)gw * H))[lane];
    const float  bfc = b_fc[gw];

    // L1 rows gw and gw+400 (K=400 -> 100 float4 chunks; lane, lane+64)
    const int k1a = lane;
    const int k1b = (lane + 64 < 100) ? lane + 64 : 99;
    float4 w1a0 = ((const float4*)(W_l1 + (size_t)gw * FCN))[k1a];
    float4 w1a1 = ((const float4*)(W_l1 + (size_t)gw * FCN))[k1b];
    if (lane + 64 >= 100) w1a1 = z4;
    const float b1a = b_l1[gw];
    const bool has2 = (gw < L1N - NWAVE);  // gw < 100
    float4 w1b0 = z4, w1b1 = z4;
    float  b1b  = 0.f;
    if (has2) {
        const float* r = W_l1 + (size_t)(gw + NWAVE) * FCN;
        w1b0 = ((const float4*)r)[k1a];
        w1b1 = ((const float4*)r)[k1b];
        if (lane + 64 >= 100) w1b1 = z4;
        b1b = b_l1[gw + NWAVE];
    }

    // L2 row gw (K=500 -> 125 float4 chunks; lane, lane+64)
    const int k2b = (lane + 64 < 125) ? lane + 64 : 124;
    float4 w2a = z4, w2b = z4;
    float  b2  = 0.f;
    if (gw < L2N) {
        const float* r = W_l2 + (size_t)gw * L1N;
        w2a = ((const float4*)r)[lane];
        w2b = ((const float4*)r)[k2b];
        if (lane + 64 >= 125) w2b = z4;
        b2 = b_l2[gw];
    }

    // ============ DATAFLOW STAGES (no barriers) ===========================
    // LSTM layer 0 from x_last
    if (lstm_role) {
        float pi = wave_reduce(dot2(wA[0][0], xv0));
        float pg = wave_reduce(dot2(wA[0][1], xv0));
        float po = wave_reduce(dot2(wA[0][2], xv0));
        if (lane == 0) {
            const float cc = sigmoidf_(pi + bA[0][0]) * tanhf(pg + bA[0][1]);
            slot_store(&slots[HB0 + gw], sigmoidf_(po + bA[0][2]) * tanhf(cc));
        }
    }

    // LSTM layers 1,2: lane polls exactly its two h elements
#pragma unroll
    for (int l = 1; l < 3; ++l) {
        if (lstm_role) {
            const int base = (l == 1) ? HB0 : HB1;
            float2 xv;
            xv.x = slot_wait(&slots[base + 2 * lane + 0]);
            xv.y = slot_wait(&slots[base + 2 * lane + 1]);
            float pi = wave_reduce(dot2(wA[l][0], xv));
            float pg = wave_reduce(dot2(wA[l][1], xv));
            float po = wave_reduce(dot2(wA[l][2], xv));
            if (lane == 0) {
                const float cc = sigmoidf_(pi + bA[l][0]) * tanhf(pg + bA[l][1]);
                slot_store(&slots[((l == 1) ? HB1 : HB2) + gw],
                           sigmoidf_(po + bA[l][2]) * tanhf(cc));
            }
        }
    }

    // FC: all 400 waves; lane polls its two h2 elements
    {
        float2 xv;
        xv.x = slot_wait(&slots[HB2 + 2 * lane + 0]);
        xv.y = slot_wait(&slots[HB2 + 2 * lane + 1]);
        float p = wave_reduce(dot2(wfc, xv));
        if (lane == 0) slot_store(&slots[FCO + gw], p + bfc);
    }

    // L1: rows gw (+ gw+400); lane polls the 8 fc elements of its chunks
    {
        float4 x0, x1;
        x0.x = slot_wait(&slots[FCO + 4 * k1a + 0]);
        x0.y = slot_wait(&slots[FCO + 4 * k1a + 1]);
        x0.z = slot_wait(&slots[FCO + 4 * k1a + 2]);
        x0.w = slot_wait(&slots[FCO + 4 * k1a + 3]);
        x1.x = slot_wait(&slots[FCO + 4 * k1b + 0]);
        x1.y = slot_wait(&slots[FCO + 4 * k1b + 1]);
        x1.z = slot_wait(&slots[FCO + 4 * k1b + 2]);
        x1.w = slot_wait(&slots[FCO + 4 * k1b + 3]);
        float acc = wave_reduce(dot4(w1a0, x0) + dot4(w1a1, x1));
        if (lane == 0) slot_store(&slots[L1O + gw], acc + b1a);
        if (has2) {
            float acc2 = wave_reduce(dot4(w1b0, x0) + dot4(w1b1, x1));
            if (lane == 0) slot_store(&slots[L1O + gw + NWAVE], acc2 + b1b);
        }
    }

    // L2 -> out: waves 0..62; lane polls the 8 l1 elements of its chunks
    if (gw < L2N) {
        float4 x0, x1;
        x0.x = slot_wait(&slots[L1O + 4 * lane + 0]);
        x0.y = slot_wait(&slots[L1O + 4 * lane + 1]);
        x0.z = slot_wait(&slots[L1O + 4 * lane + 2]);
        x0.w = slot_wait(&slots[L1O + 4 * lane + 3]);
        x1.x = slot_wait(&slots[L1O + 4 * k2b + 0]);
        x1.y = slot_wait(&slots[L1O + 4 * k2b + 1]);
        x1.z = slot_wait(&slots[L1O + 4 * k2b + 2]);
        x1.w = slot_wait(&slots[L1O + 4 * k2b + 3]);
        float acc = wave_reduce(dot4(w2a, x0) + dot4(w2b, x1));
        if (lane == 0) out[gw] = acc + b2;
    }
}

extern "C" void kernel_launch(void* const* d_in, const int* in_sizes, int n_in,
                              void* d_out, int out_size, void* d_ws, size_t ws_size,
                              hipStream_t stream) {
    const float* inputs = (const float*)d_in[0];
    const float* W_ih   = (const float*)d_in[1];
    // d_in[2] = W_hh (unused: h0 = 0)
    const float* b_ih   = (const float*)d_in[3];
    const float* b_hh   = (const float*)d_in[4];
    const float* W_fc   = (const float*)d_in[5];
    const float* b_fc   = (const float*)d_in[6];
    const float* W_l1   = (const float*)d_in[7];
    const float* b_l1   = (const float*)d_in[8];
    const float* W_l2   = (const float*)d_in[9];
    const float* b_l2   = (const float*)d_in[10];
    float* out = (float*)d_out;

    u64* slots = (u64*)d_ws;  // tags reset by the harness's 0xAA poison

    const float* x_last = inputs + (size_t)(STEPS - 1) * H;

    fused_kernel<<<NBLK, 256, 0, stream>>>(
        x_last, W_ih, b_ih, b_hh, W_fc, b_fc, W_l1, b_l1, W_l2, b_l2,
        slots, out);
}

// Round 6
// 110.364 us; speedup vs baseline: 1.1277x; 1.1277x over previous
//
#include <hip/hip_runtime.h>
#include <math.h>

#define H      128
#define FCN    400
#define L1N    500
#define L2N    63
#define STEPS  65536
#define NBLK   100
#define NWAVE  (NBLK * 4)   // 400 waves
#define TAG    0x13572468u

// slot indices into the u64 slot array in d_ws
#define HB0 0
#define HB1 128
#define HB2 256
#define FCO 384
#define L1O 784

typedef unsigned long long u64;

__device__ __forceinline__ float sigmoidf_(float v) {
    return 1.0f / (1.0f + expf(-v));
}

__device__ __forceinline__ float wave_reduce(float v) {
#pragma unroll
    for (int off = 32; off > 0; off >>= 1)
        v += __shfl_down(v, off, 64);
    return v;
}

// Tagged-slot dataflow. Tag+value share one 64-bit word, so a RELAXED store /
// RELAXED load pair is sufficient: the data IS the flag (no other memory needs
// ordering). Agent scope -> LLC, coherent across per-XCD L2s. Harness 0xAA
// poison of d_ws clears tags before every launch.
__device__ __forceinline__ u64 ld_slot(const u64* p) {
    return __hip_atomic_load(p, __ATOMIC_RELAXED, __HIP_MEMORY_SCOPE_AGENT);
}
__device__ __forceinline__ void st_slot(u64* p, float v) {
    union { float f; unsigned u; } c; c.f = v;
    __hip_atomic_store(p, ((u64)TAG << 32) | (u64)c.u,
                       __ATOMIC_RELAXED, __HIP_MEMORY_SCOPE_AGENT);
}
__device__ __forceinline__ bool tok(u64 v) { return (unsigned)(v >> 32) == TAG; }
__device__ __forceinline__ float tval(u64 v) {
    union { unsigned u; float f; } c; c.u = (unsigned)v; return c.f;
}

// Batched polls: issue ALL loads each round -> ready case = 1 LLC round trip.
__device__ __forceinline__ float2 wait2(const u64* p0, const u64* p1) {
    u64 a = ld_slot(p0), b = ld_slot(p1);
    while (!(tok(a) && tok(b))) {
        __builtin_amdgcn_s_sleep(1);
        a = ld_slot(p0); b = ld_slot(p1);
    }
    return make_float2(tval(a), tval(b));
}
__device__ __forceinline__ void wait8(const u64* base, int ka, int kb,
                                      float4* x0, float4* x1) {
    const u64* p0 = base + 4 * ka;
    const u64* p1 = base + 4 * kb;
    u64 a0, a1, a2, a3, b0, b1, b2, b3;
    for (;;) {
        a0 = ld_slot(p0 + 0); a1 = ld_slot(p0 + 1);
        a2 = ld_slot(p0 + 2); a3 = ld_slot(p0 + 3);
        b0 = ld_slot(p1 + 0); b1 = ld_slot(p1 + 1);
        b2 = ld_slot(p1 + 2); b3 = ld_slot(p1 + 3);
        if (tok(a0) && tok(a1) && tok(a2) && tok(a3) &&
            tok(b0) && tok(b1) && tok(b2) && tok(b3)) break;
        __builtin_amdgcn_s_sleep(1);
    }
    *x0 = make_float4(tval(a0), tval(a1), tval(a2), tval(a3));
    *x1 = make_float4(tval(b0), tval(b1), tval(b2), tval(b3));
}

__device__ __forceinline__ float dot2(float2 w, float2 x) {
    return fmaf(w.x, x.x, w.y * x.y);
}
__device__ __forceinline__ float dot4(float4 w, float4 x) {
    return fmaf(w.x, x.x, fmaf(w.y, x.y, fmaf(w.z, x.z, w.w * x.w)));
}

__global__ __launch_bounds__(256) void fused_kernel(
    const float* __restrict__ x_last,  // [H]
    const float* __restrict__ W_ih,    // [3, 4H, H]
    const float* __restrict__ b_ih,    // [3, 4H]
    const float* __restrict__ b_hh,    // [3, 4H]
    const float* __restrict__ W_fc,    // [FCN, H]
    const float* __restrict__ b_fc,
    const float* __restrict__ W_l1,    // [L1N, FCN]
    const float* __restrict__ b_l1,
    const float* __restrict__ W_l2,    // [L2N, L1N]
    const float* __restrict__ b_l2,
    u64* __restrict__ slots,           // ws: tagged dataflow slots
    float* __restrict__ out)           // [L2N]
{
    const int tid  = threadIdx.x;
    const int lane = tid & 63;
    const int gw   = (blockIdx.x << 2) | (tid >> 6);  // 0..399

    const float4 z4 = make_float4(0.f, 0.f, 0.f, 0.f);
    const bool lstm_role = (gw < H);  // blocks 0..31: uniform per block

    float2 wA1[3], wA2[3];
    float  bA1[3], bA2[3];

    // ---- LSTM layer 0: load ONLY its operands, compute, publish ASAP -----
    if (lstm_role) {
        const float2 xv0 = ((const float2*)x_last)[lane];
        const float2 w0i = ((const float2*)(W_ih + (size_t)(0 * H + gw) * H))[lane];
        const float2 w0g = ((const float2*)(W_ih + (size_t)(2 * H + gw) * H))[lane];
        const float2 w0o = ((const float2*)(W_ih + (size_t)(3 * H + gw) * H))[lane];
        const float bi0 = b_ih[0 * H + gw] + b_hh[0 * H + gw];
        const float bg0 = b_ih[2 * H + gw] + b_hh[2 * H + gw];
        const float bo0 = b_ih[3 * H + gw] + b_hh[3 * H + gw];
        float pi = wave_reduce(dot2(w0i, xv0));
        float pg = wave_reduce(dot2(w0g, xv0));
        float po = wave_reduce(dot2(w0o, xv0));
        if (lane == 0) {
            const float cc = sigmoidf_(pi + bi0) * tanhf(pg + bg0);
            st_slot(&slots[HB0 + gw], sigmoidf_(po + bo0) * tanhf(cc));
        }
        // keep the bulk prefetch from being scheduled above the publish
        __builtin_amdgcn_sched_barrier(0);
        // prefetch layers 1,2
#pragma unroll
        for (int l = 1; l < 3; ++l) {
            const float* Wl = W_ih + (size_t)l * 4 * H * H;
            float2* wa = (l == 1) ? wA1 : wA2;
            float*  ba = (l == 1) ? bA1 : bA2;
            wa[0] = ((const float2*)(Wl + (size_t)(0 * H + gw) * H))[lane];
            wa[1] = ((const float2*)(Wl + (size_t)(2 * H + gw) * H))[lane];
            wa[2] = ((const float2*)(Wl + (size_t)(3 * H + gw) * H))[lane];
            ba[0] = b_ih[l * 4 * H + 0 * H + gw] + b_hh[l * 4 * H + 0 * H + gw];
            ba[1] = b_ih[l * 4 * H + 2 * H + gw] + b_hh[l * 4 * H + 2 * H + gw];
            ba[2] = b_ih[l * 4 * H + 3 * H + gw] + b_hh[l * 4 * H + 3 * H + gw];
        }
    }

    // ---- prefetch FC/L1/L2 rows (no activation dependence) ---------------
    const float2 wfc = ((const float2*)(W_fc + (size_t)gw * H))[lane];
    const float  bfc = b_fc[gw];

    const int k1a = lane;                       // < 100 always
    const int k1b = (lane + 64 < 100) ? lane + 64 : 99;
    float4 w1a0 = ((const float4*)(W_l1 + (size_t)gw * FCN))[k1a];
    float4 w1a1 = ((const float4*)(W_l1 + (size_t)gw * FCN))[k1b];
    if (lane + 64 >= 100) w1a1 = z4;
    const float b1a = b_l1[gw];
    const bool has2 = (gw < L1N - NWAVE);       // gw < 100
    float4 w1b0 = z4, w1b1 = z4;
    float  b1b  = 0.f;
    if (has2) {
        const float* r = W_l1 + (size_t)(gw + NWAVE) * FCN;
        w1b0 = ((const float4*)r)[k1a];
        w1b1 = ((const float4*)r)[k1b];
        if (lane + 64 >= 100) w1b1 = z4;
        b1b = b_l1[gw + NWAVE];
    }

    const int k2b = (lane + 64 < 125) ? lane + 64 : 124;
    float4 w2a = z4, w2b = z4;
    float  b2  = 0.f;
    if (gw < L2N) {
        const float* r = W_l2 + (size_t)gw * L1N;
        w2a = ((const float4*)r)[lane];
        w2b = ((const float4*)r)[k2b];
        if (lane + 64 >= 125) w2b = z4;
        b2 = b_l2[gw];
    }

    // ---- LSTM layers 1,2: batched 2-slot polls ---------------------------
    if (lstm_role) {
#pragma unroll
        for (int l = 1; l < 3; ++l) {
            const int base = (l == 1) ? HB0 : HB1;
            const float2 xv = wait2(&slots[base + 2 * lane],
                                    &slots[base + 2 * lane + 1]);
            const float2* wa = (l == 1) ? wA1 : wA2;
            const float*  ba = (l == 1) ? bA1 : bA2;
            float pi = wave_reduce(dot2(wa[0], xv));
            float pg = wave_reduce(dot2(wa[1], xv));
            float po = wave_reduce(dot2(wa[2], xv));
            if (lane == 0) {
                const float cc = sigmoidf_(pi + ba[0]) * tanhf(pg + ba[1]);
                st_slot(&slots[((l == 1) ? HB1 : HB2) + gw],
                        sigmoidf_(po + ba[2]) * tanhf(cc));
            }
        }
    }

    // ---- FC: all 400 waves ----------------------------------------------
    {
        const float2 xv = wait2(&slots[HB2 + 2 * lane],
                                &slots[HB2 + 2 * lane + 1]);
        float p = wave_reduce(dot2(wfc, xv));
        if (lane == 0) st_slot(&slots[FCO + gw], p + bfc);
    }

    // ---- L1: rows gw (+ gw+400) -----------------------------------------
    {
        float4 x0, x1;
        wait8(&slots[FCO], k1a, k1b, &x0, &x1);
        float acc = wave_reduce(dot4(w1a0, x0) + dot4(w1a1, x1));
        if (lane == 0) st_slot(&slots[L1O + gw], acc + b1a);
        if (has2) {
            float acc2 = wave_reduce(dot4(w1b0, x0) + dot4(w1b1, x1));
            if (lane == 0) st_slot(&slots[L1O + gw + NWAVE], acc2 + b1b);
        }
    }

    // ---- L2 -> out: waves 0..62 -----------------------------------------
    if (gw < L2N) {
        float4 x0, x1;
        wait8(&slots[L1O], lane, k2b, &x0, &x1);
        float acc = wave_reduce(dot4(w2a, x0) + dot4(w2b, x1));
        if (lane == 0) out[gw] = acc + b2;
    }
}

extern "C" void kernel_launch(void* const* d_in, const int* in_sizes, int n_in,
                              void* d_out, int out_size, void* d_ws, size_t ws_size,
                              hipStream_t stream) {
    const float* inputs = (const float*)d_in[0];
    const float* W_ih   = (const float*)d_in[1];
    // d_in[2] = W_hh (unused: h0 = 0)
    const float* b_ih   = (const float*)d_in[3];
    const float* b_hh   = (const float*)d_in[4];
    const float* W_fc   = (const float*)d_in[5];
    const float* b_fc   = (const float*)d_in[6];
    const float* W_l1   = (const float*)d_in[7];
    const float* b_l1   = (const float*)d_in[8];
    const float* W_l2   = (const float*)d_in[9];
    const float* b_l2   = (const float*)d_in[10];
    float* out = (float*)d_out;

    u64* slots = (u64*)d_ws;  // tags reset by the harness's 0xAA poison

    const float* x_last = inputs + (size_t)(STEPS - 1) * H;

    fused_kernel<<<NBLK, 256, 0, stream>>>(
        x_last, W_ih, b_ih, b_hh, W_fc, b_fc, W_l1, b_l1, W_l2, b_l2,
        slots, out);
}